// Round 4
// baseline (603.262 us; speedup 1.0000x reference)
//
#include <hip/hip_runtime.h>
#include <hip/hip_bf16.h>

// Problem constants: B=256, N=128, EB=5, NA=64, DIM=512, NIT=3
// out = [logit (256 f32), graph_repr (256*512 f32)]

typedef __bf16 bf16;
typedef __bf16 bf16x4 __attribute__((ext_vector_type(4)));
typedef __bf16 bf16x8 __attribute__((ext_vector_type(8)));
typedef float floatx4 __attribute__((ext_vector_type(4)));

__device__ __forceinline__ void glds16(const void* g, void* l) {
    __builtin_amdgcn_global_load_lds((const __attribute__((address_space(1))) unsigned int*)g,
                                     (__attribute__((address_space(3))) unsigned int*)l,
                                     16, 0, 0);
}

// ---------------------------------------------------------------- Ahat[b,n,m] = sum_e adj[...,1:] + (n==m)
__global__ __launch_bounds__(256) void k_asum(const float* __restrict__ adj,
                                              bf16* __restrict__ ahat) {
    int i = blockIdx.x * 256 + threadIdx.x;   // group of 4 elements
    int base = i * 4;
    const float4* p = (const float4*)(adj + (size_t)base * 5);
    float4 v0 = p[0], v1 = p[1], v2 = p[2], v3 = p[3], v4 = p[4];
    float s[4];
    s[0] = v0.y + v0.z + v0.w + v1.x;
    s[1] = v1.z + v1.w + v2.x + v2.y;
    s[2] = v2.w + v3.x + v3.y + v3.z;
    s[3] = v4.x + v4.y + v4.z + v4.w;
    bf16x4 o;
#pragma unroll
    for (int j = 0; j < 4; j++) {
        int e = base + j;
        int m = e & 127, n = (e >> 7) & 127;
        float v = s[j] + ((n == m) ? 1.0f : 0.0f);
        o[j] = (bf16)v;
    }
    *(bf16x4*)(ahat + base) = o;
}

// ---------------------------------------------------------------- transpose [R,C] -> [C,R], out bf16 (weights only)
template <typename Tin>
__global__ __launch_bounds__(256) void k_transpose(const Tin* __restrict__ in, bf16* __restrict__ out,
                                                   int R, int C, long long sIn, long long sOut) {
    __shared__ bf16 tile[32][33];
    const Tin* src = in + (size_t)blockIdx.z * sIn;
    bf16* dst = out + (size_t)blockIdx.z * sOut;
    int c0 = blockIdx.x * 32, r0 = blockIdx.y * 32;
    int tx = threadIdx.x & 31, ty = threadIdx.x >> 5;
#pragma unroll
    for (int i = 0; i < 4; i++) {
        int r = ty + i * 8;
        tile[r][tx] = (bf16)(float)src[(size_t)(r0 + r) * C + c0 + tx];
    }
    __syncthreads();
#pragma unroll
    for (int i = 0; i < 4; i++) {
        int c = ty + i * 8;
        dst[(size_t)(c0 + c) * R + r0 + tx] = tile[tx][c];
    }
}

// ---------------------------------------------------------------- fused WLS forward
// 1024 threads (16 waves, 4/SIMD), one block per batch.
// hT global [256][512 d][128 n] round-trips h between iterations (L2-local).
// Ts (LDS 128KB) holds t[n=128][d=512], 16B-chunk swizzle: phys = c ^ (n&15).
// Sb (LDS 2x8KB) double-buffers glds staging (h^T chunks in phase 1, W chunks in phase 2).
__global__ __launch_bounds__(1024, 4) void k_mega(
    const float* __restrict__ nodef,   // [256][128][64] f32
    const bf16* __restrict__ Web_t,    // [512][64]
    const float* __restrict__ b_embed, // [512]
    const bf16* __restrict__ Ahat,     // [256][128][128]
    const bf16* __restrict__ Wlb_t,    // [3][512][512]
    const float* __restrict__ b_layers,// [3][512]
    const float* __restrict__ W_out,   // [512]
    const float* __restrict__ b_out,   // [1]
    bf16* __restrict__ hT,             // [256][512][128]
    float* __restrict__ out)           // [256 logit][256*512 graph_repr]
{
    __shared__ __align__(16) bf16 Ts[128 * 512];   // 131072 B
    __shared__ __align__(16) bf16 Sb[2][4096];     // 2 x 8192 B

    const int b = blockIdx.x;
    const int tid = threadIdx.x;
    const int lane = tid & 63, wid = tid >> 6;      // 16 waves
    const int q = lane >> 4, l16 = lane & 15;
    const int wm = wid >> 2, wn = wid & 3;          // 4x4 wave grid (phase 2 / embed)
    const int p1_dt = wid >> 3, p1_nt = wid & 7;    // phase-1: d-subtile, n-tile

    bf16* hTb = hT + (size_t)b * 65536;

    // Ahat B-frags, register-resident for all 3 iterations (n-tile = p1_nt)
    bf16x8 ahf[4];
#pragma unroll
    for (int kk = 0; kk < 4; kk++)
        ahf[kk] = *(const bf16x8*)(Ahat + (size_t)b * 16384 +
                                   (size_t)(p1_nt * 16 + l16) * 128 + kk * 32 + q * 8);

    // ---------------- embed: hT = (node @ W_embed + b_embed)^T
    {
        const float* Ab = nodef + (size_t)b * 8192;
#pragma unroll
        for (int dce = 0; dce < 2; dce++) {
            floatx4 acc[2][4] = {};
#pragma unroll
            for (int ks = 0; ks < 2; ks++) {
                bf16x8 af[2], bfr[4];
#pragma unroll
                for (int mt = 0; mt < 2; mt++) {
                    const float* src = Ab + (size_t)(wm * 32 + mt * 16 + l16) * 64 + ks * 32 + q * 8;
                    float4 x = *(const float4*)src;
                    float4 y = *(const float4*)(src + 4);
                    bf16x8 v;
                    v[0] = (bf16)x.x; v[1] = (bf16)x.y; v[2] = (bf16)x.z; v[3] = (bf16)x.w;
                    v[4] = (bf16)y.x; v[5] = (bf16)y.y; v[6] = (bf16)y.z; v[7] = (bf16)y.w;
                    af[mt] = v;
                }
#pragma unroll
                for (int nt = 0; nt < 4; nt++) {
                    int d = dce * 256 + wn * 64 + nt * 16 + l16;
                    bfr[nt] = *(const bf16x8*)(Web_t + (size_t)d * 64 + ks * 32 + q * 8);
                }
#pragma unroll
                for (int mt = 0; mt < 2; mt++)
#pragma unroll
                    for (int nt = 0; nt < 4; nt++)
                        acc[mt][nt] = __builtin_amdgcn_mfma_f32_16x16x32_bf16(af[mt], bfr[nt], acc[mt][nt], 0, 0, 0);
            }
#pragma unroll
            for (int mt = 0; mt < 2; mt++)
#pragma unroll
                for (int nt = 0; nt < 4; nt++) {
                    int d = dce * 256 + wn * 64 + nt * 16 + l16;
                    float bv = b_embed[d];
                    int n0 = wm * 32 + mt * 16 + q * 4;
                    bf16x4 pk;
#pragma unroll
                    for (int r = 0; r < 4; r++) pk[r] = (bf16)(acc[mt][nt][r] + bv);
                    *(bf16x4*)(hTb + (size_t)d * 128 + n0) = pk;
                }
        }
    }
    __threadfence();
    __syncthreads();

    float gp[8] = {};  // graph-mean partials (it==2)

    // ---------------- 3 WLS iterations
    for (int it = 0; it < 3; it++) {
        const bf16* WT = Wlb_t + (size_t)it * 262144;
        const float* bl = b_layers + it * 512;

        // ----- phase 1: Ts[n][d] = Ahat @ h   (A = h^T staged, B = Ahat regs)
        {
            // stage h^T chunk [32 d][128 m] into Sb[buf]; waves 0..7, 1 glds each
            auto stage_h = [&](int dc, int buf) {
                if (wid < 8) {
                    int p = wid * 64 + lane;
                    int r = p >> 4, c = p & 15;
                    glds16(hTb + (size_t)(dc * 32 + r) * 128 + ((c ^ (r & 15)) * 8),
                           (char*)&Sb[buf][0] + (size_t)(wid * 64) * 16);
                }
            };
            stage_h(0, 0);
            for (int dc = 0; dc < 16; dc++) {
                __syncthreads();
                if (dc + 1 < 16) stage_h(dc + 1, (dc + 1) & 1);
                const bf16* S = &Sb[dc & 1][0];
                floatx4 acc1 = {};
#pragma unroll
                for (int kk = 0; kk < 4; kk++) {
                    bf16x8 af = *(const bf16x8*)(S + (p1_dt * 16 + l16) * 128 + (((kk * 4 + q) ^ l16) * 8));
                    acc1 = __builtin_amdgcn_mfma_f32_16x16x32_bf16(af, ahf[kk], acc1, 0, 0, 0);
                }
                int n = p1_nt * 16 + l16;
                int c = dc * 4 + p1_dt * 2 + (q >> 1);
                bf16x4 pk;
#pragma unroll
                for (int r = 0; r < 4; r++) pk[r] = (bf16)acc1[r];
                *(bf16x4*)&Ts[n * 512 + ((c ^ l16) * 8) + (q & 1) * 4] = pk;
            }
            __syncthreads();
        }

        // ----- phase 2: h' = relu(t @ W + b), A = Ts, B = W^T staged via glds
        // stage W chunk [128 d'][32 d] into Sb[buf]
        auto stage_w = [&](int dc, int ks, int buf) {
            if (wid < 8) {
                int p = wid * 64 + lane;
                int r = p >> 2, c = p & 3;
                glds16(WT + (size_t)(dc * 128 + r) * 512 + ks * 32 + ((c ^ (r & 3)) * 8),
                       (char*)&Sb[buf][0] + (size_t)(wid * 64) * 16);
            }
        };
        for (int dc = 0; dc < 4; dc++) {
            floatx4 acc[2][2] = {};
            stage_w(dc, 0, 0);
            for (int ks = 0; ks < 16; ks++) {
                __syncthreads();
                if (ks + 1 < 16) stage_w(dc, ks + 1, (ks + 1) & 1);
                bf16x8 af[2], bfr[2];
#pragma unroll
                for (int mt = 0; mt < 2; mt++) {
                    int n = wm * 32 + mt * 16 + l16;
                    af[mt] = *(const bf16x8*)&Ts[n * 512 + (((ks * 4 + q) ^ l16) * 8)];
                }
                const bf16* S = &Sb[ks & 1][0];
#pragma unroll
                for (int nt = 0; nt < 2; nt++) {
                    int rB = wn * 32 + nt * 16 + l16;
                    bfr[nt] = *(const bf16x8*)(S + rB * 32 + ((q ^ (rB & 3)) * 8));
                }
#pragma unroll
                for (int mt = 0; mt < 2; mt++)
#pragma unroll
                    for (int nt = 0; nt < 2; nt++)
                        acc[mt][nt] = __builtin_amdgcn_mfma_f32_16x16x32_bf16(af[mt], bfr[nt], acc[mt][nt], 0, 0, 0);
            }
            // epilogue for this dc
#pragma unroll
            for (int nt = 0; nt < 2; nt++) {
                int dp = dc * 128 + wn * 32 + nt * 16 + l16;
                float bv = bl[dp];
                if (it < 2) {
#pragma unroll
                    for (int mt = 0; mt < 2; mt++) {
                        int n0 = wm * 32 + mt * 16 + q * 4;
                        bf16x4 pk;
#pragma unroll
                        for (int r = 0; r < 4; r++) pk[r] = (bf16)fmaxf(acc[mt][nt][r] + bv, 0.f);
                        *(bf16x4*)(hTb + (size_t)dp * 128 + n0) = pk;
                    }
                } else {
                    float s = 0.f;
#pragma unroll
                    for (int mt = 0; mt < 2; mt++)
#pragma unroll
                        for (int r = 0; r < 4; r++)
                            s += fmaxf(acc[mt][nt][r] + bv, 0.f);
                    gp[dc * 2 + nt] += s;
                }
            }
            __syncthreads();  // Sb[*] consumed before next dc restages / finalize overlay
        }
        if (it < 2) {
            __threadfence();
            __syncthreads();
        }
    }

    // ---------------- fused finalize: graph_repr = mean_n(h3), logit = repr @ W_out + b_out
    float* RsF = (float*)&Sb[0][0];               // [4 wm][512 d']
    float* lpF = (float*)((char*)&Sb[0][0] + 8192); // [512]
#pragma unroll
    for (int j = 0; j < 8; j++) {
        float v = gp[j];
        v += __shfl_down(v, 32);
        v += __shfl_down(v, 16);
        if (q == 0) RsF[wm * 512 + (j >> 1) * 128 + wn * 32 + (j & 1) * 16 + l16] = v;
    }
    __syncthreads();
    if (tid < 512) {
        float g = (RsF[tid] + RsF[512 + tid] + RsF[1024 + tid] + RsF[1536 + tid]) * (1.f / 128.f);
        out[256 + (size_t)b * 512 + tid] = g;
        lpF[tid] = g * W_out[tid];
    }
    __syncthreads();
    for (int s = 256; s > 0; s >>= 1) {
        if (tid < s) lpF[tid] += lpF[tid + s];
        __syncthreads();
    }
    if (tid == 0) out[b] = lpF[0] + b_out[0];
}

// ---------------------------------------------------------------- launch
extern "C" void kernel_launch(void* const* d_in, const int* in_sizes, int n_in,
                              void* d_out, int out_size, void* d_ws, size_t ws_size,
                              hipStream_t stream) {
    const float* adj      = (const float*)d_in[0];
    // d_in[1] = hidden (unused by forward)
    const float* node     = (const float*)d_in[2];
    const float* W_embed  = (const float*)d_in[3];
    const float* b_embed  = (const float*)d_in[4];
    const float* W_layers = (const float*)d_in[5];
    const float* b_layers = (const float*)d_in[6];
    const float* W_out    = (const float*)d_in[7];
    const float* b_out    = (const float*)d_in[8];
    float* out = (float*)d_out;

    char* ws = (char*)d_ws;
    bf16* Web_t = (bf16*)(ws);              //     65,536 B : W_embed^T bf16 [512][64]
    bf16* Wlb_t = (bf16*)(ws + 65536);      //  1,572,864 B : W_layers^T bf16 [3][512][512]
    bf16* Ahat  = (bf16*)(ws + 1638400);    //  8,388,608 B : (Asum + I) [256][128][128]
    bf16* h_t   = (bf16*)(ws + 10027008);   // 33,554,432 B : h^T [256][512][128] (end 43.6 MB)

    k_transpose<float><<<dim3(16, 2, 1), 256, 0, stream>>>(W_embed, Web_t, 64, 512, 0, 0);
    k_transpose<float><<<dim3(16, 16, 3), 256, 0, stream>>>(W_layers, Wlb_t, 512, 512, 262144, 262144);
    k_asum<<<4096, 256, 0, stream>>>(adj, Ahat);
    k_mega<<<256, 1024, 0, stream>>>(node, Web_t, b_embed, Ahat, Wlb_t, b_layers,
                                     W_out, b_out, h_t, out);
}

// Round 5
// 270.428 us; speedup vs baseline: 2.2308x; 2.2308x over previous
//
#include <hip/hip_runtime.h>
#include <hip/hip_bf16.h>

// Problem constants: B=256, N=128, EB=5, NA=64, DIM=512, NIT=3
// out = [logit (256 f32), graph_repr (256*512 f32)]

typedef __bf16 bf16;
typedef __bf16 bf16x4 __attribute__((ext_vector_type(4)));
typedef __bf16 bf16x8 __attribute__((ext_vector_type(8)));
typedef float floatx4 __attribute__((ext_vector_type(4)));

// ---------------------------------------------------------------- Ahat[b,n,m] = sum_e adj[...,1:] + (n==m)
__global__ __launch_bounds__(256) void k_asum(const float* __restrict__ adj,
                                              bf16* __restrict__ ahat) {
    int i = blockIdx.x * 256 + threadIdx.x;   // group of 4 elements
    int base = i * 4;
    const float4* p = (const float4*)(adj + (size_t)base * 5);
    float4 v0 = p[0], v1 = p[1], v2 = p[2], v3 = p[3], v4 = p[4];
    float s[4];
    s[0] = v0.y + v0.z + v0.w + v1.x;
    s[1] = v1.z + v1.w + v2.x + v2.y;
    s[2] = v2.w + v3.x + v3.y + v3.z;
    s[3] = v4.x + v4.y + v4.z + v4.w;
    bf16x4 o;
#pragma unroll
    for (int j = 0; j < 4; j++) {
        int e = base + j;
        int m = e & 127, n = (e >> 7) & 127;
        float v = s[j] + ((n == m) ? 1.0f : 0.0f);
        o[j] = (bf16)v;
    }
    *(bf16x4*)(ahat + base) = o;
}

// ---------------------------------------------------------------- transpose [R,C] -> [C,R], out bf16 (weights only)
template <typename Tin>
__global__ __launch_bounds__(256) void k_transpose(const Tin* __restrict__ in, bf16* __restrict__ out,
                                                   int R, int C, long long sIn, long long sOut) {
    __shared__ bf16 tile[32][33];
    const Tin* src = in + (size_t)blockIdx.z * sIn;
    bf16* dst = out + (size_t)blockIdx.z * sOut;
    int c0 = blockIdx.x * 32, r0 = blockIdx.y * 32;
    int tx = threadIdx.x & 31, ty = threadIdx.x >> 5;
#pragma unroll
    for (int i = 0; i < 4; i++) {
        int r = ty + i * 8;
        tile[r][tx] = (bf16)(float)src[(size_t)(r0 + r) * C + c0 + tx];
    }
    __syncthreads();
#pragma unroll
    for (int i = 0; i < 4; i++) {
        int c = ty + i * 8;
        dst[(size_t)(c0 + c) * R + r0 + tx] = tile[tx][c];
    }
}

// ---------------------------------------------------------------- fused WLS forward
// 1024 threads (16 waves, 4/SIMD), one block per batch. h lives in LDS (HT) for the
// whole kernel — no global h traffic, no glds, barriers only at phase boundaries.
//
// HT: h^T [512 d][128 n], row stride 136 bf16 (+8 pad -> b128-aligned, 2-way banks = free)
// TB: t^T chunk as t[n=128][d-local=32], row stride 40 bf16 (+8 pad)
//
// Per 32-d chunk dc:
//  ph1 (wave = dt(2) x ntw(8)): t^T tile = MFMA(A = HT rows [d][k=m], B = Ahat regs) -> TB (b64)
//  ph2 (wave = wid d'-slice of 32): acc[8][2] += MFMA(A = TB rows [n][k=d], B = W^T global b128)
//  B-frags for ph2 are loaded in the ph1 section (independent of TB) so the pre-barrier
//  vmcnt drain overlaps ph1 compute.
#define HTS 136
#define TBS 40

__global__ __launch_bounds__(1024, 4) void k_mega(
    const float* __restrict__ nodef,   // [256][128][64] f32
    const bf16* __restrict__ Web_t,    // [512][64]
    const float* __restrict__ b_embed, // [512]
    const bf16* __restrict__ Ahat,     // [256][128][128]
    const bf16* __restrict__ Wlb_t,    // [3][512][512]
    const float* __restrict__ b_layers,// [3][512]
    const float* __restrict__ W_out,   // [512]
    const float* __restrict__ b_out,   // [1]
    float* __restrict__ out)           // [256 logit][256*512 graph_repr]
{
    __shared__ __align__(16) bf16 HT[512 * HTS];   // 139264 B
    __shared__ __align__(16) bf16 TB[128 * TBS];   //  10240 B
    __shared__ float RsF[512];                     //   2048 B
    __shared__ float lpF[512];                     //   2048 B  (total 153600 B)

    const int b = blockIdx.x;
    const int tid = threadIdx.x;
    const int lane = tid & 63, wid = tid >> 6;     // 16 waves
    const int q = lane >> 4, l16 = lane & 15;

    // ---- Ahat fragments: resident in VGPRs for the whole kernel (B-operand of ph1)
    const int dt = wid >> 3, ntw = wid & 7;        // ph1 wave roles
    bf16x8 ahf[4];
#pragma unroll
    for (int kk = 0; kk < 4; kk++)
        ahf[kk] = *(const bf16x8*)(Ahat + (size_t)b * 16384 +
                                   (size_t)(ntw * 16 + l16) * 128 + kk * 32 + q * 8);

    // ---- embed: HT = (node @ W_embed + b_embed)^T  (wave grid 2 x 8, tile 64n x 64d)
    {
        const int wmE = wid >> 3, wnE = wid & 7;
        const float* Ab = nodef + (size_t)b * 8192;
        floatx4 accE[4][4] = {};
#pragma unroll
        for (int kk = 0; kk < 2; kk++) {
            bf16x8 af[4], bfr[4];
#pragma unroll
            for (int mt = 0; mt < 4; mt++) {
                const float* src = Ab + (size_t)(wmE * 64 + mt * 16 + l16) * 64 + kk * 32 + q * 8;
                float4 x = *(const float4*)src;
                float4 y = *(const float4*)(src + 4);
                bf16x8 v;
                v[0] = (bf16)x.x; v[1] = (bf16)x.y; v[2] = (bf16)x.z; v[3] = (bf16)x.w;
                v[4] = (bf16)y.x; v[5] = (bf16)y.y; v[6] = (bf16)y.z; v[7] = (bf16)y.w;
                af[mt] = v;
            }
#pragma unroll
            for (int nt = 0; nt < 4; nt++)
                bfr[nt] = *(const bf16x8*)(Web_t + (size_t)(wnE * 64 + nt * 16 + l16) * 64 + kk * 32 + q * 8);
#pragma unroll
            for (int mt = 0; mt < 4; mt++)
#pragma unroll
                for (int nt = 0; nt < 4; nt++)
                    accE[mt][nt] = __builtin_amdgcn_mfma_f32_16x16x32_bf16(af[mt], bfr[nt], accE[mt][nt], 0, 0, 0);
        }
#pragma unroll
        for (int mt = 0; mt < 4; mt++)
#pragma unroll
            for (int nt = 0; nt < 4; nt++) {
                int d = wnE * 64 + nt * 16 + l16;
                float bv = b_embed[d];
                int n0 = wmE * 64 + mt * 16 + q * 4;
                bf16x4 pk;
#pragma unroll
                for (int r = 0; r < 4; r++) pk[r] = (bf16)(accE[mt][nt][r] + bv);
                *(bf16x4*)&HT[d * HTS + n0] = pk;
            }
    }
    __syncthreads();

    // ---------------- 3 WLS iterations
    for (int it = 0; it < 3; it++) {
        const bf16* WT = Wlb_t + (size_t)it * 262144;
        const float* bl = b_layers + it * 512;
        floatx4 acc[8][2] = {};

        for (int dc = 0; dc < 16; dc++) {
            // ----- ph1: t^T[dc-chunk] -> TB
            floatx4 a1 = {};
            {
                int drow = dc * 32 + dt * 16 + l16;
#pragma unroll
                for (int kk = 0; kk < 4; kk++) {
                    bf16x8 af = *(const bf16x8*)&HT[drow * HTS + kk * 32 + q * 8];
                    a1 = __builtin_amdgcn_mfma_f32_16x16x32_bf16(af, ahf[kk], a1, 0, 0, 0);
                }
            }
            // ph2 B-frags: independent of TB; issued here so the barrier drain overlaps ph1
            bf16x8 bfr[2];
#pragma unroll
            for (int nt = 0; nt < 2; nt++)
                bfr[nt] = *(const bf16x8*)(WT + (size_t)(wid * 32 + nt * 16 + l16) * 512 + dc * 32 + q * 8);
            {
                bf16x4 pk;
#pragma unroll
                for (int r = 0; r < 4; r++) pk[r] = (bf16)a1[r];
                *(bf16x4*)&TB[(ntw * 16 + l16) * TBS + dt * 16 + q * 4] = pk;
            }
            __syncthreads();

            // ----- ph2: acc += t[dc-chunk] @ W[dc-chunk]  (wave owns 32 d'-columns)
#pragma unroll
            for (int mt = 0; mt < 8; mt++) {
                bf16x8 af2 = *(const bf16x8*)&TB[(mt * 16 + l16) * TBS + q * 8];
#pragma unroll
                for (int nt = 0; nt < 2; nt++)
                    acc[mt][nt] = __builtin_amdgcn_mfma_f32_16x16x32_bf16(af2, bfr[nt], acc[mt][nt], 0, 0, 0);
            }
            __syncthreads();
        }

        if (it < 2) {
            // h'^T = relu(acc + bias) -> HT (b64 rows)
#pragma unroll
            for (int nt = 0; nt < 2; nt++) {
                int dp = wid * 32 + nt * 16 + l16;
                float bv = bl[dp];
#pragma unroll
                for (int mt = 0; mt < 8; mt++) {
                    int n0 = mt * 16 + q * 4;
                    bf16x4 pk;
#pragma unroll
                    for (int r = 0; r < 4; r++) pk[r] = (bf16)fmaxf(acc[mt][nt][r] + bv, 0.f);
                    *(bf16x4*)&HT[dp * HTS + n0] = pk;
                }
            }
            __syncthreads();
        } else {
            // fused mean over n: each (wave, nt, l16) owns one d' column
#pragma unroll
            for (int nt = 0; nt < 2; nt++) {
                int dp = wid * 32 + nt * 16 + l16;
                float bv = bl[dp];
                float s = 0.f;
#pragma unroll
                for (int mt = 0; mt < 8; mt++)
#pragma unroll
                    for (int r = 0; r < 4; r++)
                        s += fmaxf(acc[mt][nt][r] + bv, 0.f);
                s += __shfl_down(s, 32);
                s += __shfl_down(s, 16);
                if (lane < 16) RsF[wid * 32 + nt * 16 + lane] = s;
            }
        }
    }
    __syncthreads();

    // ---------------- finalize: graph_repr + logit
    if (tid < 512) {
        float g = RsF[tid] * (1.f / 128.f);
        out[256 + (size_t)b * 512 + tid] = g;
        lpF[tid] = g * W_out[tid];
    }
    __syncthreads();
    for (int s = 256; s > 0; s >>= 1) {
        if (tid < s) lpF[tid] += lpF[tid + s];
        __syncthreads();
    }
    if (tid == 0) out[b] = lpF[0] + b_out[0];
}

// ---------------------------------------------------------------- launch
extern "C" void kernel_launch(void* const* d_in, const int* in_sizes, int n_in,
                              void* d_out, int out_size, void* d_ws, size_t ws_size,
                              hipStream_t stream) {
    const float* adj      = (const float*)d_in[0];
    // d_in[1] = hidden (unused by forward)
    const float* node     = (const float*)d_in[2];
    const float* W_embed  = (const float*)d_in[3];
    const float* b_embed  = (const float*)d_in[4];
    const float* W_layers = (const float*)d_in[5];
    const float* b_layers = (const float*)d_in[6];
    const float* W_out    = (const float*)d_in[7];
    const float* b_out    = (const float*)d_in[8];
    float* out = (float*)d_out;

    char* ws = (char*)d_ws;
    bf16* Web_t = (bf16*)(ws);              //     65,536 B : W_embed^T bf16 [512][64]
    bf16* Wlb_t = (bf16*)(ws + 65536);      //  1,572,864 B : W_layers^T bf16 [3][512][512]
    bf16* Ahat  = (bf16*)(ws + 1638400);    //  8,388,608 B : (Asum + I) [256][128][128] (end 10 MB)

    k_transpose<float><<<dim3(16, 2, 1), 256, 0, stream>>>(W_embed, Web_t, 64, 512, 0, 0);
    k_transpose<float><<<dim3(16, 16, 3), 256, 0, stream>>>(W_layers, Wlb_t, 512, 512, 262144, 262144);
    k_asum<<<4096, 256, 0, stream>>>(adj, Ahat);
    k_mega<<<256, 1024, 0, stream>>>(node, Web_t, b_embed, Ahat, Wlb_t, b_layers,
                                     W_out, b_out, out);
}